// Round 1
// baseline (346.862 us; speedup 1.0000x reference)
//
#include <hip/hip_runtime.h>

// MHSA without softmax => fully linear:
//   qkv = x^T @ W + b                       [4096, 1536]
//   M_h = K_h^T V_h  (64x64 per head), qsum_h = sum_q Q_h[q,:]
//   output_h = SCALE * Q_h @ M_h            [4096, 64]
//   coarse_h[n] = SCALE * K_h[n,:] . qsum_h [4096]
// Avoids the O(N^2) attention matrix entirely.

#define N_TOK 4096
#define EMBED 512
#define J3    1536   // 3*EMBED
#define HEADS 8
#define DH    64
#define SCALE 0.125f

// ---------------- Pass 1: qkv[n][j] = b[j] + sum_e x[e][n] * W[e][j] ----------------
// x is [512, 4096] (e-major, since input is [1,512,64,64]); W is [512, 1536].
__global__ __launch_bounds__(256) void qkv_gemm(const float* __restrict__ x,
                                                const float* __restrict__ W,
                                                const float* __restrict__ b,
                                                float* __restrict__ qkv) {
    __shared__ float As[16][64];   // [e][n]
    __shared__ float Bs[16][64];   // [e][j]
    const int j0 = blockIdx.x * 64;   // 24 tiles
    const int n0 = blockIdx.y * 64;   // 64 tiles
    const int tid = threadIdx.x;
    const int tx = tid & 15, ty = tid >> 4;
    float c[4][4] = {};
    for (int e0 = 0; e0 < EMBED; e0 += 16) {
        #pragma unroll
        for (int k = 0; k < 4; ++k) {
            int e  = (tid >> 6) + 4 * k;   // 0..15
            int nl = tid & 63;             // 0..63, coalesced
            As[e][nl] = x[(e0 + e) * N_TOK + n0 + nl];
            Bs[e][nl] = W[(e0 + e) * J3 + j0 + nl];
        }
        __syncthreads();
        #pragma unroll
        for (int e = 0; e < 16; ++e) {
            float a[4], bb[4];
            #pragma unroll
            for (int i = 0; i < 4; ++i) a[i] = As[e][ty + 16 * i];
            #pragma unroll
            for (int j = 0; j < 4; ++j) bb[j] = Bs[e][tx + 16 * j];
            #pragma unroll
            for (int i = 0; i < 4; ++i)
                #pragma unroll
                for (int j = 0; j < 4; ++j)
                    c[i][j] += a[i] * bb[j];
        }
        __syncthreads();
    }
    #pragma unroll
    for (int i = 0; i < 4; ++i) {
        int n = n0 + ty + 16 * i;
        #pragma unroll
        for (int j = 0; j < 4; ++j) {
            int jj = j0 + tx + 16 * j;
            qkv[n * J3 + jj] = c[i][j] + b[jj];
        }
    }
}

// ---------------- Pass 2: M[h][dp][d] += sum_n k[n][dp]*v[n][d];  qsum[h][dp] += sum_n q[n][dp]
__global__ __launch_bounds__(256) void kv_reduce(const float* __restrict__ qkv,
                                                 float* __restrict__ M,
                                                 float* __restrict__ qsum) {
    const int h  = blockIdx.x;           // 8
    const int n0 = blockIdx.y * 64;      // 64 chunks of 64 rows
    const int tid = threadIdx.x;
    __shared__ float Ks[64][64];
    __shared__ float Vs[64][64];
    __shared__ float qred[256];
    #pragma unroll
    for (int k = 0; k < 16; ++k) {
        int idx = tid + 256 * k;         // 0..4095
        int n = idx >> 6, d2 = idx & 63; // coalesced along d2
        Ks[n][d2] = qkv[(n0 + n) * J3 + EMBED     + h * DH + d2];
        Vs[n][d2] = qkv[(n0 + n) * J3 + 2 * EMBED + h * DH + d2];
    }
    // qsum partial: thread -> (d = tid%64, 16 rows)
    {
        const int d   = tid & 63;
        const int nr0 = (tid >> 6) * 16;
        float qa = 0.f;
        for (int n = nr0; n < nr0 + 16; ++n)
            qa += qkv[(n0 + n) * J3 + h * DH + d];
        qred[tid] = qa;
    }
    __syncthreads();
    // each thread owns 16 entries of the 64x64 M tile: dp = tid/4, d = (tid%4)*16 + p
    const int dp    = tid >> 2;
    const int dbase = (tid & 3) * 16;
    float acc[16] = {};
    for (int n = 0; n < 64; ++n) {
        float kv = Ks[n][dp];
        #pragma unroll
        for (int p = 0; p < 16; ++p)
            acc[p] += kv * Vs[n][dbase + p];
    }
    #pragma unroll
    for (int p = 0; p < 16; ++p)
        atomicAdd(&M[h * (DH * DH) + dp * DH + dbase + p], acc[p]);
    if (tid < 64)
        atomicAdd(&qsum[h * DH + tid],
                  qred[tid] + qred[tid + 64] + qred[tid + 128] + qred[tid + 192]);
}

// ---------------- Pass 3: output + coarse ----------------
__global__ __launch_bounds__(256) void out_gemm(const float* __restrict__ qkv,
                                                const float* __restrict__ M,
                                                const float* __restrict__ qsum,
                                                float* __restrict__ out) {
    const int h  = blockIdx.x;
    const int n0 = blockIdx.y * 64;
    const int tid = threadIdx.x;
    __shared__ float Ms[64][64];
    __shared__ float Qs[64][64];
    __shared__ float qs[64];
    #pragma unroll
    for (int k = 0; k < 16; ++k) {
        int idx = tid + 256 * k;
        int a = idx >> 6, d2 = idx & 63;
        Ms[a][d2] = M[h * (DH * DH) + idx];
        Qs[a][d2] = qkv[(n0 + a) * J3 + h * DH + d2];
    }
    if (tid < 64) qs[tid] = qsum[h * DH + tid];
    __syncthreads();
    const int d = tid & 63;
    float* outp = out + HEADS * N_TOK + h * (N_TOK * DH);  // coarse first, then output
    #pragma unroll
    for (int i = 0; i < 16; ++i) {
        int r = (tid >> 6) * 16 + i;     // wave-uniform row
        float acc = 0.f;
        #pragma unroll
        for (int dp = 0; dp < 64; ++dp)
            acc += Qs[r][dp] * Ms[dp][d];
        outp[(n0 + r) * DH + d] = acc * SCALE;
    }
    if (tid < 64) {
        int n = n0 + tid;
        float acc = 0.f;
        #pragma unroll
        for (int dp = 0; dp < 64; ++dp)
            acc += qkv[n * J3 + EMBED + h * DH + dp] * qs[dp];
        out[h * N_TOK + n] = acc * SCALE;
    }
}

extern "C" void kernel_launch(void* const* d_in, const int* in_sizes, int n_in,
                              void* d_out, int out_size, void* d_ws, size_t ws_size,
                              hipStream_t stream) {
    const float* x = (const float*)d_in[0];   // [1,512,64,64]
    const float* W = (const float*)d_in[1];   // [512,1536]
    const float* b = (const float*)d_in[2];   // [1536]
    float* out  = (float*)d_out;              // coarse [8,4096] then output [8,4096,64]
    float* qkv  = (float*)d_ws;                         // 4096*1536 floats
    float* M    = qkv + (size_t)N_TOK * J3;             // 8*64*64 floats
    float* qsum = M + HEADS * DH * DH;                  // 8*64 floats

    // ws is poisoned 0xAA before every launch; zero the accumulators
    hipMemsetAsync(M, 0, (HEADS * DH * DH + HEADS * DH) * sizeof(float), stream);

    qkv_gemm<<<dim3(J3 / 64, N_TOK / 64), 256, 0, stream>>>(x, W, b, qkv);
    kv_reduce<<<dim3(HEADS, N_TOK / 64), 256, 0, stream>>>(qkv, M, qsum);
    out_gemm<<<dim3(HEADS, N_TOK / 64), 256, 0, stream>>>(qkv, M, qsum, out);
}

// Round 2
// 117.345 us; speedup vs baseline: 2.9559x; 2.9559x over previous
//
#include <hip/hip_runtime.h>

// Linear MHSA (no softmax):
//   qkv = x^T W + b   (bf16 MFMA)         [4096, 1536]
//   M_h = K_h^T V_h   (64x64/head, partials + tree reduce; NO atomics)
//   out_h = SCALE * Q_h M_h ; coarse_h[n] = SCALE * K_h[n]·(sum_q Q_h[q])

#define N_TOK 4096
#define EMBED 512
#define J3    1536
#define HEADS 8
#define DH    64
#define SCALE 0.125f

typedef float  floatx4  __attribute__((ext_vector_type(4)));
typedef short  shortx8  __attribute__((ext_vector_type(8)));
typedef unsigned short ushortx4 __attribute__((ext_vector_type(4)));

__device__ inline unsigned short f2bf(float f) {
    union { float f; unsigned int u; } x; x.f = f;
    unsigned int u = x.u;
    unsigned int r = u + 0x7fffu + ((u >> 16) & 1u);   // RNE
    return (unsigned short)(r >> 16);
}
__device__ inline float bf2f(unsigned short u) {
    union { unsigned int u; float f; } x; x.u = ((unsigned int)u) << 16; return x.f;
}

// ---------- transpose + fp32->bf16: src[512][C] -> dst[C][512] ----------
__global__ __launch_bounds__(256) void tr_cvt(const float* __restrict__ src,
                                              unsigned short* __restrict__ dst, int C) {
    __shared__ float T[64][65];
    const int c0 = blockIdx.x * 64, r0 = blockIdx.y * 64;
    const int t = threadIdx.x;
    #pragma unroll
    for (int k = 0; k < 16; ++k) {
        int i = t + 256 * k; int r = i >> 6, c = i & 63;
        T[r][c] = src[(size_t)(r0 + r) * C + c0 + c];
    }
    __syncthreads();
    #pragma unroll
    for (int k = 0; k < 16; ++k) {
        int i = t + 256 * k; int cr = i >> 6, cc = i & 63;   // dst row c0+cr, col r0+cc
        dst[(size_t)(c0 + cr) * 512 + r0 + cc] = f2bf(T[cc][cr]);
    }
}

// ---------- qkv GEMM: D[n][j] = sum_e xT[n][e]*WT[j][e] + b[j], bf16 MFMA ----------
// 128x128 tile, BK=32, 4 waves (2x2), each wave 64x64 via 4x4 mfma_16x16x32
__global__ __launch_bounds__(256) void qkv_mfma(const unsigned short* __restrict__ xT,
                                                const unsigned short* __restrict__ WT,
                                                const float* __restrict__ bias,
                                                unsigned short* __restrict__ qkv) {
    __shared__ __align__(16) short As[128 * 32];   // [row n][32 e], 64B rows, contiguous
    __shared__ __align__(16) short Bs[128 * 32];   // [row j][32 e]
    const int j0 = blockIdx.x * 128, n0 = blockIdx.y * 128;
    const int t = threadIdx.x, lane = t & 63, w = t >> 6;
    const int wm = w & 1, wn = w >> 1;
    const int quad = lane >> 4, mrow = lane & 15;
    floatx4 acc[4][4] = {};
    for (int e0 = 0; e0 < 512; e0 += 32) {
        __syncthreads();   // previous iter's readers done
        #pragma unroll
        for (int s = 0; s < 2; ++s) {
            int i = t + 256 * s;                 // 0..511 ushort8-units
            int row = i >> 2, q = i & 3;         // 128 rows x 4 units
            shortx8 av = *(const shortx8*)(xT + (size_t)(n0 + row) * 512 + e0 + q * 8);
            shortx8 bv = *(const shortx8*)(WT + (size_t)(j0 + row) * 512 + e0 + q * 8);
            *(shortx8*)&As[row * 32 + q * 8] = av;
            *(shortx8*)&Bs[row * 32 + q * 8] = bv;
        }
        __syncthreads();
        shortx8 a[4], b[4];
        #pragma unroll
        for (int mi = 0; mi < 4; ++mi)
            a[mi] = *(const shortx8*)&As[(wm * 64 + mi * 16 + mrow) * 32 + quad * 8];
        #pragma unroll
        for (int ni = 0; ni < 4; ++ni)
            b[ni] = *(const shortx8*)&Bs[(wn * 64 + ni * 16 + mrow) * 32 + quad * 8];
        #pragma unroll
        for (int mi = 0; mi < 4; ++mi)
            #pragma unroll
            for (int ni = 0; ni < 4; ++ni)
                acc[mi][ni] = __builtin_amdgcn_mfma_f32_16x16x32_bf16(a[mi], b[ni], acc[mi][ni], 0, 0, 0);
    }
    // C/D: col = lane&15, row = (lane>>4)*4 + reg
    const int col = lane & 15, qr = lane >> 4;
    #pragma unroll
    for (int ni = 0; ni < 4; ++ni) {
        int j = j0 + wn * 64 + ni * 16 + col;
        float bj = bias[j];
        #pragma unroll
        for (int mi = 0; mi < 4; ++mi)
            #pragma unroll
            for (int r = 0; r < 4; ++r) {
                int n = n0 + wm * 64 + mi * 16 + qr * 4 + r;
                qkv[(size_t)n * J3 + j] = f2bf(acc[mi][ni][r] + bj);
            }
    }
}

// ---------- pass 2 partials: Mp[h][ch] = sum_{n in chunk} K[n]^T V[n]; qsp likewise ----------
__global__ __launch_bounds__(256) void kv_partial(const unsigned short* __restrict__ qkv,
                                                  float* __restrict__ Mp, float* __restrict__ qsp) {
    const int h = blockIdx.x, ch = blockIdx.y;   // 8 x 32, 128 tokens each
    const int n0 = ch * 128;
    __shared__ __align__(16) float Ks[64][68];
    __shared__ __align__(16) float Vs[64][68];
    __shared__ float qred[256];
    const int t = threadIdx.x;
    const int tx = t & 15, ty = t >> 4;          // d0 = tx*4, dp0 = ty*4
    float acc[4][4] = {};
    float qa = 0.f;
    for (int st = 0; st < 2; ++st) {
        const int nb = n0 + st * 64;
        __syncthreads();
        #pragma unroll
        for (int k = 0; k < 4; ++k) {
            int i = t + 256 * k; int row = i >> 4, c4 = (i & 15) * 4;
            ushortx4 k4 = *(const ushortx4*)(qkv + (size_t)(nb + row) * J3 + EMBED + h * DH + c4);
            ushortx4 v4 = *(const ushortx4*)(qkv + (size_t)(nb + row) * J3 + 2 * EMBED + h * DH + c4);
            Ks[row][c4 + 0] = bf2f(k4[0]); Ks[row][c4 + 1] = bf2f(k4[1]);
            Ks[row][c4 + 2] = bf2f(k4[2]); Ks[row][c4 + 3] = bf2f(k4[3]);
            Vs[row][c4 + 0] = bf2f(v4[0]); Vs[row][c4 + 1] = bf2f(v4[1]);
            Vs[row][c4 + 2] = bf2f(v4[2]); Vs[row][c4 + 3] = bf2f(v4[3]);
        }
        {   // Q row-sum partial (global, coalesced over d)
            int d = t & 63, q0 = (t >> 6) * 16;
            for (int n = q0; n < q0 + 16; ++n)
                qa += bf2f(qkv[(size_t)(nb + n) * J3 + h * DH + d]);
        }
        __syncthreads();
        for (int n = 0; n < 64; ++n) {
            floatx4 kf = *(const floatx4*)&Ks[n][ty * 4];
            floatx4 vf = *(const floatx4*)&Vs[n][tx * 4];
            #pragma unroll
            for (int i = 0; i < 4; ++i)
                #pragma unroll
                for (int j = 0; j < 4; ++j)
                    acc[i][j] += kf[i] * vf[j];
        }
    }
    qred[t] = qa;
    __syncthreads();
    float* mp = Mp + ((size_t)h * 32 + ch) * 4096;
    #pragma unroll
    for (int i = 0; i < 4; ++i) {
        floatx4 v = { acc[i][0], acc[i][1], acc[i][2], acc[i][3] };
        *(floatx4*)&mp[(ty * 4 + i) * 64 + tx * 4] = v;
    }
    if (t < 64)
        qsp[((size_t)h * 32 + ch) * 64 + t] = qred[t] + qred[t + 64] + qred[t + 128] + qred[t + 192];
}

// ---------- tree-reduce partials ----------
__global__ __launch_bounds__(256) void reduce_md(const float* __restrict__ Mp,
                                                 const float* __restrict__ qsp,
                                                 float* __restrict__ M, float* __restrict__ qsum) {
    const int b = blockIdx.x;            // 32: h = b>>2, part = b&3
    const int h = b >> 2, part = b & 3;
    const int t = threadIdx.x;
    #pragma unroll
    for (int k = 0; k < 4; ++k) {
        int i = part * 1024 + t + 256 * k;
        float s = 0.f;
        for (int c = 0; c < 32; ++c) s += Mp[((size_t)h * 32 + c) * 4096 + i];
        M[h * 4096 + i] = s;
    }
    if (part == 0 && t < 64) {
        float s = 0.f;
        for (int c = 0; c < 32; ++c) s += qsp[((size_t)h * 32 + c) * 64 + t];
        qsum[h * DH + t] = s;
    }
}

// ---------- pass 3: out = SCALE*Q M ; coarse = SCALE*K.qsum ----------
__global__ __launch_bounds__(256) void out_kernel(const unsigned short* __restrict__ qkv,
                                                  const float* __restrict__ M,
                                                  const float* __restrict__ qsum,
                                                  float* __restrict__ out) {
    const int h = blockIdx.x, ch = blockIdx.y;   // 8 x 64, 64 tokens each
    const int n0 = ch * 64;
    __shared__ __align__(16) float Ms[64][68];
    __shared__ __align__(16) float Qs[64][68];
    __shared__ unsigned short Kb[64][66];
    __shared__ float qs[64];
    __shared__ float cred[256];
    const int t = threadIdx.x;
    #pragma unroll
    for (int k = 0; k < 4; ++k) {
        int i = t + 256 * k; int row = i >> 4, c4 = (i & 15) * 4;
        floatx4 mv = *(const floatx4*)&M[h * 4096 + row * 64 + c4];
        *(floatx4*)&Ms[row][c4] = mv;
        ushortx4 q4 = *(const ushortx4*)(qkv + (size_t)(n0 + row) * J3 + h * DH + c4);
        Qs[row][c4 + 0] = bf2f(q4[0]); Qs[row][c4 + 1] = bf2f(q4[1]);
        Qs[row][c4 + 2] = bf2f(q4[2]); Qs[row][c4 + 3] = bf2f(q4[3]);
    }
    #pragma unroll
    for (int k = 0; k < 16; ++k) {
        int i = t + 256 * k; int row = i >> 6, col = i & 63;
        Kb[row][col] = qkv[(size_t)(n0 + row) * J3 + EMBED + h * DH + col];
    }
    if (t < 64) qs[t] = qsum[h * DH + t];
    __syncthreads();
    const int tx = t & 15, ty = t >> 4;          // d0 = tx*4, r0 = ty*4
    float acc[4][4] = {};
    for (int dp = 0; dp < 64; ++dp) {
        floatx4 mf = *(const floatx4*)&Ms[dp][tx * 4];
        float q0 = Qs[ty * 4 + 0][dp], q1 = Qs[ty * 4 + 1][dp];
        float q2 = Qs[ty * 4 + 2][dp], q3 = Qs[ty * 4 + 3][dp];
        #pragma unroll
        for (int j = 0; j < 4; ++j) {
            acc[0][j] += q0 * mf[j]; acc[1][j] += q1 * mf[j];
            acc[2][j] += q2 * mf[j]; acc[3][j] += q3 * mf[j];
        }
    }
    float* op = out + HEADS * N_TOK + (size_t)h * N_TOK * DH;
    #pragma unroll
    for (int i = 0; i < 4; ++i) {
        int n = n0 + ty * 4 + i;
        floatx4 v = { acc[i][0] * SCALE, acc[i][1] * SCALE, acc[i][2] * SCALE, acc[i][3] * SCALE };
        *(floatx4*)&op[(size_t)n * DH + tx * 4] = v;
    }
    // coarse
    {
        int cn = t & 63, part = t >> 6;
        float ca = 0.f;
        for (int dp = part * 16; dp < part * 16 + 16; ++dp)
            ca += bf2f(Kb[cn][dp]) * qs[dp];
        cred[t] = ca;
    }
    __syncthreads();
    if (t < 64)
        out[h * N_TOK + n0 + t] = (cred[t] + cred[t + 64] + cred[t + 128] + cred[t + 192]) * SCALE;
}

extern "C" void kernel_launch(void* const* d_in, const int* in_sizes, int n_in,
                              void* d_out, int out_size, void* d_ws, size_t ws_size,
                              hipStream_t stream) {
    const float* x = (const float*)d_in[0];   // [512][4096]
    const float* W = (const float*)d_in[1];   // [512][1536]
    const float* b = (const float*)d_in[2];   // [1536]
    float* out = (float*)d_out;

    unsigned short* xT   = (unsigned short*)d_ws;                 // [4096][512]
    unsigned short* WT   = xT + (size_t)N_TOK * EMBED;            // [1536][512]
    unsigned short* qkvb = WT + (size_t)J3 * EMBED;               // [4096][1536]
    float* Mp   = (float*)(qkvb + (size_t)N_TOK * J3);            // [8][32][4096]
    float* qsp  = Mp + (size_t)HEADS * 32 * 4096;                 // [8][32][64]
    float* M    = qsp + (size_t)HEADS * 32 * 64;                  // [8][4096]
    float* qsum = M + (size_t)HEADS * 4096;                       // [8][64]

    tr_cvt<<<dim3(64, 8), 256, 0, stream>>>(x, xT, N_TOK);
    tr_cvt<<<dim3(24, 8), 256, 0, stream>>>(W, WT, J3);
    qkv_mfma<<<dim3(12, 32), 256, 0, stream>>>(xT, WT, b, qkvb);
    kv_partial<<<dim3(8, 32), 256, 0, stream>>>(qkvb, Mp, qsp);
    reduce_md<<<32, 256, 0, stream>>>(Mp, qsp, M, qsum);
    out_kernel<<<dim3(8, 64), 256, 0, stream>>>(qkvb, M, qsum, out);
}

// Round 3
// 107.425 us; speedup vs baseline: 3.2289x; 1.0923x over previous
//
#include <hip/hip_runtime.h>

// Linear MHSA (no softmax):
//   qkv = x^T W + b   (bf16 MFMA, global_load_lds staging)
//   M_h = K_h^T V_h   (chunk partials, no atomics) -> Mt bf16 transposed
//   out_h = SCALE * Q_h M_h   (LDS-free MFMA from global)
//   coarse_h[n] = SCALE * K_h[n] . (sum_q Q_h[q])

#define N_TOK 4096
#define EMBED 512
#define J3    1536
#define HEADS 8
#define DH    64
#define SCALE 0.125f

typedef float  floatx4  __attribute__((ext_vector_type(4)));
typedef short  shortx8  __attribute__((ext_vector_type(8)));
typedef unsigned short ushortx4 __attribute__((ext_vector_type(4)));
typedef unsigned short ushortx2 __attribute__((ext_vector_type(2)));
typedef unsigned int u32;

__device__ inline unsigned short f2bf(float f) {
    union { float f; u32 u; } x; x.f = f;
    u32 r = x.u + 0x7fffu + ((x.u >> 16) & 1u);   // RNE
    return (unsigned short)(r >> 16);
}
__device__ inline float bf2f(unsigned short u) {
    union { u32 u; float f; } x; x.u = ((u32)u) << 16; return x.f;
}
__device__ static inline void async_copy16(void* lds, const void* g) {
    auto* gp = (const __attribute__((address_space(1))) u32*)g;
    auto* lp = (__attribute__((address_space(3))) u32*)lds;
    __builtin_amdgcn_global_load_lds(gp, lp, 16, 0, 0);
}

// ---------- transpose + fp32->bf16 for BOTH x and W in one launch ----------
__global__ __launch_bounds__(256) void tr_cvt(const float* __restrict__ x,
                                              const float* __restrict__ W,
                                              unsigned short* __restrict__ xT,
                                              unsigned short* __restrict__ WT) {
    const float* src; unsigned short* dst; int C, bx = blockIdx.x;
    if (bx < 64) { src = x; dst = xT; C = N_TOK; }
    else         { src = W; dst = WT; C = J3; bx -= 64; }
    __shared__ float T[64][65];
    const int c0 = bx * 64, r0 = blockIdx.y * 64;
    const int t = threadIdx.x;
    #pragma unroll
    for (int k = 0; k < 16; ++k) {
        int i = t + 256 * k; int r = i >> 6, c = i & 63;
        T[r][c] = src[(size_t)(r0 + r) * C + c0 + c];
    }
    __syncthreads();
    #pragma unroll
    for (int k = 0; k < 4; ++k) {
        int i = t + 256 * k; int cr = i >> 4, cc4 = (i & 15) * 4;
        ushortx4 o = { f2bf(T[cc4 + 0][cr]), f2bf(T[cc4 + 1][cr]),
                       f2bf(T[cc4 + 2][cr]), f2bf(T[cc4 + 3][cr]) };
        *(ushortx4*)&dst[(size_t)(c0 + cr) * 512 + r0 + cc4] = o;
    }
}

// ---------- qkv GEMM: 128x128 tile, BK=32, global_load_lds(16B) staging ----------
__global__ __launch_bounds__(256) void qkv_mfma(const unsigned short* __restrict__ xT,
                                                const unsigned short* __restrict__ WT,
                                                const float* __restrict__ bias,
                                                unsigned short* __restrict__ qkv) {
    __shared__ __align__(16) short As[128 * 32];   // [n][32e], linear in lane order
    __shared__ __align__(16) short Bs[128 * 32];   // [j][32e]
    const int j0 = blockIdx.x * 128, n0 = blockIdx.y * 128;
    const int t = threadIdx.x, lane = t & 63, w = t >> 6;
    const int wm = w & 1, wn = w >> 1;
    const int quad = lane >> 4, mrow = lane & 15;
    floatx4 acc[4][4] = {};
    for (int e0 = 0; e0 < 512; e0 += 32) {
        __syncthreads();   // prior readers done before LDS overwrite
        #pragma unroll
        for (int s = 0; s < 2; ++s) {
            int i = t + 256 * s;                   // 0..511 16B-units
            int row = i >> 2, q = i & 3;
            char* abase = (char*)As + (size_t)w * 1024 + (size_t)s * 4096;  // wave-uniform
            char* bbase = (char*)Bs + (size_t)w * 1024 + (size_t)s * 4096;
            async_copy16(abase, xT + (size_t)(n0 + row) * 512 + e0 + q * 8);
            async_copy16(bbase, WT + (size_t)(j0 + row) * 512 + e0 + q * 8);
        }
        __syncthreads();   // vmcnt(0) drain inserted by compiler
        shortx8 a[4], b[4];
        #pragma unroll
        for (int mi = 0; mi < 4; ++mi)
            a[mi] = *(const shortx8*)&As[(wm * 64 + mi * 16 + mrow) * 32 + quad * 8];
        #pragma unroll
        for (int ni = 0; ni < 4; ++ni)
            b[ni] = *(const shortx8*)&Bs[(wn * 64 + ni * 16 + mrow) * 32 + quad * 8];
        #pragma unroll
        for (int mi = 0; mi < 4; ++mi)
            #pragma unroll
            for (int ni = 0; ni < 4; ++ni)
                acc[mi][ni] = __builtin_amdgcn_mfma_f32_16x16x32_bf16(a[mi], b[ni], acc[mi][ni], 0, 0, 0);
    }
    const int col = lane & 15, qr = lane >> 4;     // C/D: col=lane&15, row=qr*4+r
    #pragma unroll
    for (int ni = 0; ni < 4; ++ni) {
        int j = j0 + wn * 64 + ni * 16 + col;
        float bj = bias[j];
        #pragma unroll
        for (int mi = 0; mi < 4; ++mi)
            #pragma unroll
            for (int r = 0; r < 4; ++r) {
                int n = n0 + wm * 64 + mi * 16 + qr * 4 + r;
                qkv[(size_t)n * J3 + j] = f2bf(acc[mi][ni][r] + bj);
            }
    }
}

// ---------- pass 2 partials: 64-token chunks (grid 8x64 = 512 blocks) ----------
__global__ __launch_bounds__(256) void kv_partial(const unsigned short* __restrict__ qkv,
                                                  float* __restrict__ Mp, float* __restrict__ qsp) {
    const int h = blockIdx.x, ch = blockIdx.y;
    const int n0 = ch * 64;
    __shared__ __align__(16) float Ks[64][68];
    __shared__ __align__(16) float Vs[64][68];
    __shared__ float qred[256];
    const int t = threadIdx.x;
    #pragma unroll
    for (int k = 0; k < 2; ++k) {
        int i = t + 256 * k; int row = i >> 3, c8 = (i & 7) * 8;
        shortx8 k8 = *(const shortx8*)(qkv + (size_t)(n0 + row) * J3 + EMBED + h * DH + c8);
        shortx8 v8 = *(const shortx8*)(qkv + (size_t)(n0 + row) * J3 + 2 * EMBED + h * DH + c8);
        #pragma unroll
        for (int j = 0; j < 8; ++j) {
            Ks[row][c8 + j] = bf2f((unsigned short)k8[j]);
            Vs[row][c8 + j] = bf2f((unsigned short)v8[j]);
        }
    }
    {   // Q column-sum partial (coalesced over d)
        int d = t & 63, q0 = (t >> 6) * 16;
        float qa = 0.f;
        for (int n = q0; n < q0 + 16; ++n)
            qa += bf2f(qkv[(size_t)(n0 + n) * J3 + h * DH + d]);
        qred[t] = qa;
    }
    __syncthreads();
    const int tx = t & 15, ty = t >> 4;            // d0 = tx*4, dp0 = ty*4
    float acc[4][4] = {};
    for (int n = 0; n < 64; ++n) {
        floatx4 kf = *(const floatx4*)&Ks[n][ty * 4];
        floatx4 vf = *(const floatx4*)&Vs[n][tx * 4];
        #pragma unroll
        for (int i = 0; i < 4; ++i)
            #pragma unroll
            for (int j = 0; j < 4; ++j)
                acc[i][j] += kf[i] * vf[j];
    }
    float* mp = Mp + ((size_t)h * 64 + ch) * 4096;
    #pragma unroll
    for (int i = 0; i < 4; ++i) {
        floatx4 v = { acc[i][0], acc[i][1], acc[i][2], acc[i][3] };
        *(floatx4*)&mp[(ty * 4 + i) * 64 + tx * 4] = v;
    }
    if (t < 64)
        qsp[((size_t)h * 64 + ch) * 64 + t] = qred[t] + qred[t + 64] + qred[t + 128] + qred[t + 192];
}

// ---------- reduce partials -> Mt (bf16, transposed [h][d][dp]) + qsum ----------
__global__ __launch_bounds__(256) void reduce_md(const float* __restrict__ Mp,
                                                 const float* __restrict__ qsp,
                                                 unsigned short* __restrict__ Mt,
                                                 float* __restrict__ qsum) {
    const int h = blockIdx.x, part = blockIdx.y;   // (8,4)
    const int t = threadIdx.x;
    __shared__ float Msh[16][68];                  // [dp_local][d]
    const int i0 = part * 1024 + t * 4;            // dp = part*16 + (t>>4), d0 = (t&15)*4
    floatx4 s = {0.f, 0.f, 0.f, 0.f};
    #pragma unroll 4
    for (int c = 0; c < 64; ++c)
        s += *(const floatx4*)&Mp[((size_t)h * 64 + c) * 4096 + i0];
    const int dpl = t >> 4, d0 = (t & 15) * 4;
    *(floatx4*)&Msh[dpl][d0] = s;
    __syncthreads();
    {   // write Mt[h][d*64 + part*16 + dpl], 8B stores
        int d = t >> 2, dpl0 = (t & 3) * 4;
        ushortx4 o = { f2bf(Msh[dpl0 + 0][d]), f2bf(Msh[dpl0 + 1][d]),
                       f2bf(Msh[dpl0 + 2][d]), f2bf(Msh[dpl0 + 3][d]) };
        *(ushortx4*)&Mt[(size_t)h * 4096 + d * 64 + part * 16 + dpl0] = o;
    }
    if (part == 0 && t < 64) {
        float q = 0.f;
        for (int c = 0; c < 64; ++c) q += qsp[((size_t)h * 64 + c) * 64 + t];
        qsum[h * DH + t] = q;
    }
}

// ---------- pass 3: LDS-free MFMA out = SCALE*Q*Mt^T ; coarse ----------
__global__ __launch_bounds__(64) void out_kernel(const unsigned short* __restrict__ qkv,
                                                 const unsigned short* __restrict__ Mt,
                                                 const float* __restrict__ qsum,
                                                 float* __restrict__ out) {
    const int h = blockIdx.x, n0 = blockIdx.y * 64;
    const int lane = threadIdx.x;
    const int quad = lane >> 4, mrow = lane & 15;
    floatx4 acc[4][4] = {};
    #pragma unroll
    for (int ks = 0; ks < 2; ++ks) {
        shortx8 a[4], b[4];
        #pragma unroll
        for (int mi = 0; mi < 4; ++mi)
            a[mi] = *(const shortx8*)(qkv + (size_t)(n0 + mi * 16 + mrow) * J3 + h * DH + ks * 32 + quad * 8);
        #pragma unroll
        for (int ni = 0; ni < 4; ++ni)
            b[ni] = *(const shortx8*)(Mt + (size_t)h * 4096 + (ni * 16 + mrow) * 64 + ks * 32 + quad * 8);
        #pragma unroll
        for (int mi = 0; mi < 4; ++mi)
            #pragma unroll
            for (int ni = 0; ni < 4; ++ni)
                acc[mi][ni] = __builtin_amdgcn_mfma_f32_16x16x32_bf16(a[mi], b[ni], acc[mi][ni], 0, 0, 0);
    }
    float* op = out + HEADS * N_TOK + (size_t)h * N_TOK * DH;
    #pragma unroll
    for (int mi = 0; mi < 4; ++mi)
        #pragma unroll
        for (int r = 0; r < 4; ++r) {
            int n = n0 + mi * 16 + quad * 4 + r;
            #pragma unroll
            for (int ni = 0; ni < 4; ++ni)
                op[(size_t)n * DH + ni * 16 + mrow] = acc[mi][ni][r] * SCALE;
        }
    // coarse: token n0+lane
    float ca = 0.f;
    #pragma unroll
    for (int g = 0; g < 8; ++g) {
        shortx8 kk = *(const shortx8*)(qkv + (size_t)(n0 + lane) * J3 + EMBED + h * DH + g * 8);
        #pragma unroll
        for (int j = 0; j < 8; ++j)
            ca += bf2f((unsigned short)kk[j]) * qsum[h * DH + g * 8 + j];
    }
    out[h * N_TOK + n0 + lane] = ca * SCALE;
}

extern "C" void kernel_launch(void* const* d_in, const int* in_sizes, int n_in,
                              void* d_out, int out_size, void* d_ws, size_t ws_size,
                              hipStream_t stream) {
    const float* x = (const float*)d_in[0];   // [512][4096]
    const float* W = (const float*)d_in[1];   // [512][1536]
    const float* b = (const float*)d_in[2];   // [1536]
    float* out = (float*)d_out;

    unsigned short* xT   = (unsigned short*)d_ws;                 // [4096][512]
    unsigned short* WT   = xT + (size_t)N_TOK * EMBED;            // [1536][512]
    unsigned short* qkvb = WT + (size_t)J3 * EMBED;               // [4096][1536]
    unsigned short* Mt   = qkvb + (size_t)N_TOK * J3;             // [8][64][64] bf16
    float* Mp   = (float*)(Mt + (size_t)HEADS * DH * DH);         // [8][64][4096]
    float* qsp  = Mp + (size_t)HEADS * 64 * 4096;                 // [8][64][64]
    float* qsum = qsp + (size_t)HEADS * 64 * 64;                  // [8][64]

    tr_cvt<<<dim3(88, 8), 256, 0, stream>>>(x, W, xT, WT);
    qkv_mfma<<<dim3(12, 32), 256, 0, stream>>>(xT, WT, b, qkvb);
    kv_partial<<<dim3(8, 64), 256, 0, stream>>>(qkvb, Mp, qsp);
    reduce_md<<<dim3(8, 4), 256, 0, stream>>>(Mp, qsp, Mt, qsum);
    out_kernel<<<dim3(8, 64), 64, 0, stream>>>(qkvb, Mt, qsum, out);
}